// Round 1
// baseline (1017.546 us; speedup 1.0000x reference)
//
#include <hip/hip_runtime.h>
#include <stdint.h>

// MarkovChain FFBS: B=64, T=1024, K=512, I=4
// R12 = R11 + backward restructure:
//   - one WAVE per (run, chain) unit: no block barriers, no LDS reduce;
//     chains decoupled, lane l owns k=8l..8l+7 -> float4 msg/ptp loads.
//   - dynamic work stealing over runCount*4 units via global cursor,
//     next-unit atomicAdd prefetched under current unit's compute.
//   - wave argmax: fmaxf butterfly + ballot/ffs (tie -> lowest lane =
//     lowest k; identical tie semantics to R11's val/idx tree).
//   - fill_out folded into backward_run prologue (one fewer dispatch).
//   - V1 (initp @ P) parallelized: 512 blocks, block-per-column tree
//     reduce (was 2 blocks x serial 512-dot gating the power chain).
// Per-k values bit-identical to R11 (same threefry/gumbel/e-mapping).

#define JAX_PARTITIONABLE 1

#define B_ 64
#define T_ 1024
#define K_ 512
#define I_ 4
#define NCHAIN (B_ * I_)
#define POWSLOT (513 * 512)   // rows 0..511 = P^L, row 512 = init_p @ P^L
#define LMAX_WANT 8
#define MAXRUNS 32769
#define BWD_BLOCKS 2048

typedef double f64x4 __attribute__((ext_vector_type(4)));

// ---------------- Threefry-2x32-20 (exact jax semantics) ----------------
__host__ __device__ inline void tf2x32(uint32_t k0, uint32_t k1, uint32_t c0, uint32_t c1,
                                       uint32_t& o0, uint32_t& o1) {
  uint32_t ks2 = k0 ^ k1 ^ 0x1BD11BDAu;
  uint32_t x0 = c0 + k0;
  uint32_t x1 = c1 + k1;
#define TFR(r) { x0 += x1; x1 = (x1 << (r)) | (x1 >> (32 - (r))); x1 ^= x0; }
  TFR(13) TFR(15) TFR(26) TFR(6)
  x0 += k1; x1 += ks2 + 1u;
  TFR(17) TFR(29) TFR(16) TFR(24)
  x0 += ks2; x1 += k0 + 2u;
  TFR(13) TFR(15) TFR(26) TFR(6)
  x0 += k0; x1 += k1 + 3u;
  TFR(17) TFR(29) TFR(16) TFR(24)
  x0 += k1; x1 += ks2 + 4u;
  TFR(13) TFR(15) TFR(26) TFR(6)
  x0 += ks2; x1 += k0 + 5u;
#undef TFR
  o0 = x0; o1 = x1;
}

__device__ inline uint32_t rng_bits(uint32_t kj0, uint32_t kj1, uint32_t e) {
#if JAX_PARTITIONABLE
  uint32_t a, b;
  tf2x32(kj0, kj1, 0u, e, a, b);
  return a ^ b;
#else
  const uint32_t HALF = (uint32_t)(NCHAIN * K_ / 2);
  uint32_t a, b;
  if (e < HALF) { tf2x32(kj0, kj1, e, e + HALF, a, b); return a; }
  else          { tf2x32(kj0, kj1, e - HALF, e, a, b); return b; }
#endif
}

// gumbel scale factor: G = -1/log(u) > 0, so that w*G is a monotone image of
// log(w) + (-log(-log u)). Branch-free log, <=2ulp RELATIVE everywhere
// (incl. u->1: e=0 path computes log(m) via exact m-1 and atanh series).
__device__ inline float gumbel_scale(uint32_t bits) {
  float f = __uint_as_float((bits >> 9) | 0x3F800000u) - 1.0f;
  float u = f + 1.17549435e-38f;            // u in [2^-126, 1)
  int iu = __float_as_int(u);
  float ef = (float)((iu >> 23) - 127);
  float m = __int_as_float((iu & 0x007fffff) | 0x3f800000);   // [1,2)
  int big = m > 1.41421356f;                // reduce to [~0.707, ~1.414)
  m = big ? m * 0.5f : m;
  ef = big ? ef + 1.0f : ef;
  float fm = m - 1.0f;                      // exact (Sterbenz)
  float r = fm * __builtin_amdgcn_rcpf(m + 1.0f);   // atanh arg, |r|<=0.172
  float r2 = r * r;
  float p = fmaf(r2, fmaf(r2, fmaf(r2, fmaf(r2, 0.11111111f, 0.14285715f),
                                   0.2f), 0.33333334f), 1.0f);
  float logu = fmaf(ef, 0.69314718f, (r + r) * p);  // < 0 strictly
  return -__builtin_amdgcn_rcpf(logu);
}

__device__ inline void step_key(uint32_t ks0, uint32_t ks1, int j, uint32_t& kj0, uint32_t& kj1) {
#if JAX_PARTITIONABLE
  tf2x32(ks0, ks1, 0u, (uint32_t)j, kj0, kj1);
#else
  const int N = T_ - 1;
  uint32_t o0, o1;
  int v = 2 * j;
  if (v < N) { tf2x32(ks0, ks1, (uint32_t)v, (uint32_t)(v + N), o0, o1); kj0 = o0; }
  else       { tf2x32(ks0, ks1, (uint32_t)(v - N), (uint32_t)v, o0, o1); kj0 = o1; }
  v = 2 * j + 1;
  if (v < N) { tf2x32(ks0, ks1, (uint32_t)v, (uint32_t)(v + N), o0, o1); kj1 = o0; }
  else       { tf2x32(ks0, ks1, (uint32_t)(v - N), (uint32_t)v, o0, o1); kj1 = o1; }
#endif
}

// ---------------- Fused setup: transpose(+1/K), V1, step keys ----------------
// blk 0..1023: copy/transpose; blk 1024..1535: V1 column dots; blk 1536..1539: keys
__global__ __launch_bounds__(256) void setup_fused(
    const float* __restrict__ P, const float* __restrict__ initp,
    float* __restrict__ POW0, float* __restrict__ PTp,
    float* __restrict__ INITROW, float* __restrict__ V1,
    int* __restrict__ runCount, int* __restrict__ maxLdev, int* __restrict__ cursor,
    uint32_t* __restrict__ KEY0, uint32_t* __restrict__ KEY1,
    uint32_t ks0, uint32_t ks1) {
  int blk = blockIdx.x;
  if (blk < 1024) {
    int id = blk * 256 + threadIdx.x;
    int r = id >> 9, c = id & 511;
    float v = P[id];
    POW0[id] = v;
    PTp[c * 512 + r] = v + 0.001953125f;   // + 1/K, bit-identical to inline add
    if (id < 512) INITROW[id] = initp[id];
    if (id == 0) { *runCount = 0; *maxLdev = 1; *cursor = 0; }
  } else if (blk < 1536) {
    // V1[c] = sum_j initp[j] * P[j][c], f64 tree-reduce, block per column
    int c = blk - 1024;
    int t = threadIdx.x;
    double acc = (double)initp[t] * (double)P[t * 512 + c]
               + (double)initp[t + 256] * (double)P[(t + 256) * 512 + c];
#pragma unroll
    for (int o = 32; o >= 1; o >>= 1) acc += __shfl_down(acc, o);
    __shared__ double sred[4];
    if ((t & 63) == 0) sred[t >> 6] = acc;
    __syncthreads();
    if (t == 0) V1[c] = (float)((sred[0] + sred[1]) + (sred[2] + sred[3]));
  } else {
    int j = (blk - 1536) * 256 + threadIdx.x;
    if (j < T_ - 1) {
      uint32_t a, b;
      step_key(ks0, ks1, j, a, b);
      KEY0[j] = a; KEY1[j] = b;
    }
  }
}

// Parallel per-b scan: message offsets, run extraction, maxL.
__global__ __launch_bounds__(1024) void setup_offsets_par(
    const int* __restrict__ data, const float* __restrict__ masks,
    int* __restrict__ off, int lmax, int initoff,
    int* __restrict__ runs, int* __restrict__ runCount, int* __restrict__ maxLdev) {
  __shared__ int prevObs[1024];
  __shared__ int nextObs[1024];
  int b = blockIdx.x;
  int t = threadIdx.x;
  bool obs = masks[b * T_ + t] > 0.0f;
  prevObs[t] = obs ? t : -1;
  nextObs[t] = obs ? t : T_;
  __syncthreads();
  for (int o = 1; o < 1024; o <<= 1) {
    int pv = (t >= o) ? prevObs[t - o] : -1;
    int nv = (t + o < 1024) ? nextObs[t + o] : T_;
    __syncthreads();
    if (pv > prevObs[t]) prevObs[t] = pv;
    if (nv < nextObs[t]) nextObs[t] = nv;
    __syncthreads();
  }
  int t0 = (t > 0) ? prevObs[t - 1] : -1;
  int idx = b * T_ + t;
  if (obs) off[idx] = -1;
  else if (t0 >= 0) {
    int L = t - t0; if (L > lmax) L = lmax;
    off[idx] = (L - 1) * POWSLOT + data[b * T_ + t0] * 512;
  } else if (t == 0) off[idx] = initoff;
  else {
    int L = t; if (L > lmax) L = lmax;
    off[idx] = (L - 1) * POWSLOT + 512 * 512;   // init-chain V row
  }
  if (!obs && t <= T_ - 2 && (t == 0 || masks[b * T_ + t - 1] > 0.0f)) {
    int te = nextObs[t] - 1; if (te > T_ - 2) te = T_ - 2;
    int r = atomicAdd(runCount, 1);
    if (r < MAXRUNS) {
      runs[r] = (b << 20) | (t << 10) | te;
      int maxL = (t == 0) ? te : (te - t + 1);
      if (maxL > 1) atomicMax(maxLdev, maxL);
    }
  }
}

// ---------------- Power GEMM via f64 MFMA (self-calibrating D layout) ----------------
// 32x32 block tile, 4 waves (2x2 of 16x16), Kc=32 chunks.
__global__ __launch_bounds__(256) void power_gemm_mfma(float* __restrict__ POW, int m,
                                                       int lmax, const int* __restrict__ maxLdev) {
  int y = blockIdx.y;
  {
    int gate = *maxLdev; if (gate > lmax) gate = lmax;
    if (y + 1 + m > gate) return;
  }
  const float* A  = POW + (size_t)y * POWSLOT;
  const float* Bm = POW + (size_t)(m - 1) * POWSLOT;
  float* C        = POW + (size_t)(y + m) * POWSLOT;
  __shared__ double As[32][33];   // [k][r]
  __shared__ double Bs[32][33];   // [k][c]
  int tid = threadIdx.x;
  int lane = tid & 63;
  int wv = tid >> 6;              // wave 0..3
  int wr = wv >> 1, wc = wv & 1;  // 2x2 wave grid
  int q = lane >> 4, r16 = lane & 15;
  int r0 = (blockIdx.x >> 4) * 32;   // 17 row tiles cover 513 rows
  int c0 = (blockIdx.x & 15) * 32;   // 16 col tiles

  // --- calibrate D mapping: (lane,reg) -> (i,j). Exact integer probes. ---
  f64x4 z = {0.0, 0.0, 0.0, 0.0};
  f64x4 d1 = __builtin_amdgcn_mfma_f64_16x16x4f64((double)r16, 1.0, z, 0, 0, 0);   // D=4i
  f64x4 d2 = __builtin_amdgcn_mfma_f64_16x16x4f64(1.0, (double)r16, z, 0, 0, 0);   // D=4j
  int ir[4], ic[4];
#pragma unroll
  for (int v = 0; v < 4; ++v) {
    ir[v] = (((int)d1[v]) >> 2) & 15;
    ic[v] = (((int)d2[v]) >> 2) & 15;
  }

  // staging: thread loads 4 consecutive f32 of an A row and a B row.
  int sr = tid >> 3;                 // 0..31
  int sk4 = (tid & 7) * 4;           // 0,4,..,28
  int ar = r0 + sr; if (ar > 512) ar = 512;   // clamp (stores guarded)

  f64x4 acc = {0.0, 0.0, 0.0, 0.0};
  for (int kc = 0; kc < 512; kc += 32) {
    float4 av = *(const float4*)(A + (size_t)ar * 512 + kc + sk4);
    float4 bv = *(const float4*)(Bm + (size_t)(kc + sr) * 512 + c0 + sk4);
    __syncthreads();                 // previous chunk's reads done
    As[sk4 + 0][sr] = (double)av.x;
    As[sk4 + 1][sr] = (double)av.y;
    As[sk4 + 2][sr] = (double)av.z;
    As[sk4 + 3][sr] = (double)av.w;
    Bs[sr][sk4 + 0] = (double)bv.x;
    Bs[sr][sk4 + 1] = (double)bv.y;
    Bs[sr][sk4 + 2] = (double)bv.z;
    Bs[sr][sk4 + 3] = (double)bv.w;
    __syncthreads();
#pragma unroll
    for (int ks = 0; ks < 8; ++ks) {
      double a = As[ks * 4 + q][wr * 16 + r16];   // A[m=r16][k=ks*4+q]
      double b = Bs[ks * 4 + q][wc * 16 + r16];   // B[k][n=r16]
      acc = __builtin_amdgcn_mfma_f64_16x16x4f64(a, b, acc, 0, 0, 0);
    }
  }
#pragma unroll
  for (int v = 0; v < 4; ++v) {
    int gr = r0 + wr * 16 + ir[v];
    int gc = c0 + wc * 16 + ic[v];
    if (gr < 513) C[(size_t)gr * 512 + gc] = (float)acc[v];
  }
}

// ---------------- Backward sampling: wave-per-(run,chain), work stealing ----------------
// Lane l owns k = 8l..8l+7 (float4x2 msg/ptp loads). Argmax via fmaxf
// butterfly + ballot (lowest lane with max = smallest k; within-lane scan
// keeps smallest j). Per-k values bit-identical to R11.
__global__ __launch_bounds__(256, 8) void backward_run(
    const int* __restrict__ data, const float* __restrict__ masks,
    const float* __restrict__ wsF, const int* __restrict__ off,
    const float* __restrict__ PTp,
    const uint32_t* __restrict__ KEY0, const uint32_t* __restrict__ KEY1,
    const int* __restrict__ runs, const int* __restrict__ runCount,
    int* __restrict__ cursor, int* __restrict__ out) {
  // folded fill_out: deterministic outputs (observed t, and t = T-1)
  {
    int id = blockIdx.x * 256 + threadIdx.x;
    if (id < NCHAIN * T_) {
      int t = id & (T_ - 1);
      int b = id >> 12;               // id>>10 = chain, chain>>2 = b
      if (t == T_ - 1 || masks[b * T_ + t] > 0.0f) out[id] = data[b * T_ + t];
    }
  }
  int lane = threadIdx.x & 63;
  int total = *runCount;
  if (total > MAXRUNS) total = MAXRUNS;
  total <<= 2;                        // units = runs x 4 chains
  int u;
  {
    int g = 0;
    if (lane == 0) g = atomicAdd(cursor, 1);
    u = __shfl(g, 0);
  }
  const float* wsL = wsF + (lane << 3);
  const float* ptL = PTp + (lane << 3);
  while (u < total) {
    int nxt = 0;
    if (lane == 0) nxt = atomicAdd(cursor, 1);   // prefetch; consumed at loop end
    int run = runs[u >> 2];
    int ci = u & 3;
    int b = run >> 20, ta = (run >> 10) & 1023, tb = run & 1023;
    int s = data[b * T_ + tb + 1];    // mask=1 or t=T-1: deterministic anchor
    uint32_t ebase = ((uint32_t)b << 11) | ((uint32_t)ci << 9) | ((uint32_t)(lane << 3));
    const int* offb = off + b * T_;
    int* outp = out + (((b << 2) | ci) * T_);
    for (int t = tb; t >= ta; --t) {
      int j = (T_ - 2) - t;
      uint32_t kj0 = KEY0[j], kj1 = KEY1[j];
      int o = offb[t];
      float4 m0 = *(const float4*)(wsL + o);
      float4 m1 = *(const float4*)(wsL + o + 4);
      const float* prow = ptL + ((size_t)s << 9);
      float4 p0 = *(const float4*)(prow);
      float4 p1 = *(const float4*)(prow + 4);
      float x0 = fmaf(m0.x, p0.x, 1e-20f) * gumbel_scale(rng_bits(kj0, kj1, ebase + 0u));
      float x1 = fmaf(m0.y, p0.y, 1e-20f) * gumbel_scale(rng_bits(kj0, kj1, ebase + 1u));
      float x2 = fmaf(m0.z, p0.z, 1e-20f) * gumbel_scale(rng_bits(kj0, kj1, ebase + 2u));
      float x3 = fmaf(m0.w, p0.w, 1e-20f) * gumbel_scale(rng_bits(kj0, kj1, ebase + 3u));
      float x4 = fmaf(m1.x, p1.x, 1e-20f) * gumbel_scale(rng_bits(kj0, kj1, ebase + 4u));
      float x5 = fmaf(m1.y, p1.y, 1e-20f) * gumbel_scale(rng_bits(kj0, kj1, ebase + 5u));
      float x6 = fmaf(m1.z, p1.z, 1e-20f) * gumbel_scale(rng_bits(kj0, kj1, ebase + 6u));
      float x7 = fmaf(m1.w, p1.w, 1e-20f) * gumbel_scale(rng_bits(kj0, kj1, ebase + 7u));
      // local argmax, strict > keeps smallest j on ties
      float bv = x0; int bj = 0;
      if (x1 > bv) { bv = x1; bj = 1; }
      if (x2 > bv) { bv = x2; bj = 2; }
      if (x3 > bv) { bv = x3; bj = 3; }
      if (x4 > bv) { bv = x4; bj = 4; }
      if (x5 > bv) { bv = x5; bj = 5; }
      if (x6 > bv) { bv = x6; bj = 6; }
      if (x7 > bv) { bv = x7; bj = 7; }
      // wave max (butterfly -> all lanes hold identical max)
      float wm = bv;
#pragma unroll
      for (int d = 1; d < 64; d <<= 1) wm = fmaxf(wm, __shfl_xor(wm, d));
      unsigned long long bal = __ballot(bv == wm);
      int wl = __ffsll(bal) - 1;       // lowest lane with the max = smallest k
      int jw = __shfl(bj, wl);
      s = (wl << 3) + jw;              // uniform across wave
      if (lane == 0) outp[t] = s;
    }
    u = __shfl(nxt, 0);
  }
}

// ---------------- Launcher ----------------
extern "C" void kernel_launch(void* const* d_in, const int* in_sizes, int n_in,
                              void* d_out, int out_size, void* d_ws, size_t ws_size,
                              hipStream_t stream) {
  const int* data = (const int*)d_in[0];
  const float* masks = (const float*)d_in[1];
  const float* initp = (const float*)d_in[2];
  const float* P = (const float*)d_in[3];
  int* out = (int*)d_out;

  int lmax = LMAX_WANT;
  {
    long long fixed = 512LL * 512 + 512 + (long long)B_ * T_ + 2 * (T_ - 1) + MAXRUNS + 64;
    long long avail = (long long)(ws_size / 4) - fixed;
    long long fit = avail / POWSLOT;
    if (fit < lmax) lmax = (fit < 1) ? 1 : (int)fit;
  }
  float* wsF = (float*)d_ws;
  float* POW = wsF;
  float* PTp = wsF + (size_t)lmax * POWSLOT;
  float* INITROW = PTp + 512 * 512;
  int* off = (int*)(INITROW + 512);
  uint32_t* KEY0 = (uint32_t*)(off + B_ * T_);
  uint32_t* KEY1 = KEY0 + (T_ - 1);
  int* runs = (int*)(KEY1 + (T_ - 1));
  int* runCount = runs + MAXRUNS;
  int* maxLdev = runCount + 1;
  int* cursor = runCount + 2;
  int initoff = lmax * POWSLOT + 512 * 512;   // INITROW position in floats

  uint32_t ks0, ks1;
#if JAX_PARTITIONABLE
  tf2x32(0u, 42u, 0u, 1u, ks0, ks1);
#else
  {
    uint32_t a0, b0, a1, b1;
    tf2x32(0u, 42u, 0u, 2u, a0, b0);
    tf2x32(0u, 42u, 1u, 3u, a1, b1);
    ks0 = b0; ks1 = b1;
  }
#endif

  hipLaunchKernelGGL(setup_fused, dim3(1540), dim3(256), 0, stream,
                     P, initp, POW, PTp, INITROW, POW + 512 * 512,
                     runCount, maxLdev, cursor, KEY0, KEY1, ks0, ks1);
  hipLaunchKernelGGL(setup_offsets_par, dim3(B_), dim3(1024), 0, stream,
                     data, masks, off, lmax, initoff, runs, runCount, maxLdev);
  int m = 1;
  while (m < lmax) {
    int count = lmax - m; if (count > m) count = m;
    hipLaunchKernelGGL(power_gemm_mfma, dim3(17 * 16, count), dim3(256), 0, stream,
                       POW, m, lmax, maxLdev);
    m += count;
  }
  hipLaunchKernelGGL(backward_run, dim3(BWD_BLOCKS), dim3(256), 0, stream,
                     data, masks, wsF, off, PTp, KEY0, KEY1, runs, runCount, cursor, out);
}

// Round 2
// 319.146 us; speedup vs baseline: 3.1883x; 3.1883x over previous
//
#include <hip/hip_runtime.h>
#include <stdint.h>

// MarkovChain FFBS: B=64, T=1024, K=512, I=4
// R13 = R12 with the global work-stealing cursor REMOVED (it serialized
// ~73K same-address device atomics ~= 880us; VALUBusy 20% matched
// work/atomic-wall exactly). Static strided assignment instead:
//   wave wid handles units wid, wid+NW, ... (NW = 32768 waves).
//   Bonus: block x gets units 4x..4x+3 = the 4 chains of run x ->
//   msg row shared in L1/L2, all 4 waves exit together.
// Everything else identical to R12 (wave-per-unit, no barriers/LDS,
// float4 msg/ptp loads, ballot argmax, folded fill_out, parallel V1).
// Per-k values bit-identical to R11/R12 (same threefry/gumbel/e-map).

#define JAX_PARTITIONABLE 1

#define B_ 64
#define T_ 1024
#define K_ 512
#define I_ 4
#define NCHAIN (B_ * I_)
#define POWSLOT (513 * 512)   // rows 0..511 = P^L, row 512 = init_p @ P^L
#define LMAX_WANT 8
#define MAXRUNS 32769
#define BWD_BLOCKS 8192

typedef double f64x4 __attribute__((ext_vector_type(4)));

// ---------------- Threefry-2x32-20 (exact jax semantics) ----------------
__host__ __device__ inline void tf2x32(uint32_t k0, uint32_t k1, uint32_t c0, uint32_t c1,
                                       uint32_t& o0, uint32_t& o1) {
  uint32_t ks2 = k0 ^ k1 ^ 0x1BD11BDAu;
  uint32_t x0 = c0 + k0;
  uint32_t x1 = c1 + k1;
#define TFR(r) { x0 += x1; x1 = (x1 << (r)) | (x1 >> (32 - (r))); x1 ^= x0; }
  TFR(13) TFR(15) TFR(26) TFR(6)
  x0 += k1; x1 += ks2 + 1u;
  TFR(17) TFR(29) TFR(16) TFR(24)
  x0 += ks2; x1 += k0 + 2u;
  TFR(13) TFR(15) TFR(26) TFR(6)
  x0 += k0; x1 += k1 + 3u;
  TFR(17) TFR(29) TFR(16) TFR(24)
  x0 += k1; x1 += ks2 + 4u;
  TFR(13) TFR(15) TFR(26) TFR(6)
  x0 += ks2; x1 += k0 + 5u;
#undef TFR
  o0 = x0; o1 = x1;
}

__device__ inline uint32_t rng_bits(uint32_t kj0, uint32_t kj1, uint32_t e) {
#if JAX_PARTITIONABLE
  uint32_t a, b;
  tf2x32(kj0, kj1, 0u, e, a, b);
  return a ^ b;
#else
  const uint32_t HALF = (uint32_t)(NCHAIN * K_ / 2);
  uint32_t a, b;
  if (e < HALF) { tf2x32(kj0, kj1, e, e + HALF, a, b); return a; }
  else          { tf2x32(kj0, kj1, e - HALF, e, a, b); return b; }
#endif
}

// gumbel scale factor: G = -1/log(u) > 0, so that w*G is a monotone image of
// log(w) + (-log(-log u)). Branch-free log, <=2ulp RELATIVE everywhere
// (incl. u->1: e=0 path computes log(m) via exact m-1 and atanh series).
__device__ inline float gumbel_scale(uint32_t bits) {
  float f = __uint_as_float((bits >> 9) | 0x3F800000u) - 1.0f;
  float u = f + 1.17549435e-38f;            // u in [2^-126, 1)
  int iu = __float_as_int(u);
  float ef = (float)((iu >> 23) - 127);
  float m = __int_as_float((iu & 0x007fffff) | 0x3f800000);   // [1,2)
  int big = m > 1.41421356f;                // reduce to [~0.707, ~1.414)
  m = big ? m * 0.5f : m;
  ef = big ? ef + 1.0f : ef;
  float fm = m - 1.0f;                      // exact (Sterbenz)
  float r = fm * __builtin_amdgcn_rcpf(m + 1.0f);   // atanh arg, |r|<=0.172
  float r2 = r * r;
  float p = fmaf(r2, fmaf(r2, fmaf(r2, fmaf(r2, 0.11111111f, 0.14285715f),
                                   0.2f), 0.33333334f), 1.0f);
  float logu = fmaf(ef, 0.69314718f, (r + r) * p);  // < 0 strictly
  return -__builtin_amdgcn_rcpf(logu);
}

__device__ inline void step_key(uint32_t ks0, uint32_t ks1, int j, uint32_t& kj0, uint32_t& kj1) {
#if JAX_PARTITIONABLE
  tf2x32(ks0, ks1, 0u, (uint32_t)j, kj0, kj1);
#else
  const int N = T_ - 1;
  uint32_t o0, o1;
  int v = 2 * j;
  if (v < N) { tf2x32(ks0, ks1, (uint32_t)v, (uint32_t)(v + N), o0, o1); kj0 = o0; }
  else       { tf2x32(ks0, ks1, (uint32_t)(v - N), (uint32_t)v, o0, o1); kj0 = o1; }
  v = 2 * j + 1;
  if (v < N) { tf2x32(ks0, ks1, (uint32_t)v, (uint32_t)(v + N), o0, o1); kj1 = o0; }
  else       { tf2x32(ks0, ks1, (uint32_t)(v - N), (uint32_t)v, o0, o1); kj1 = o1; }
#endif
}

// ---------------- Fused setup: transpose(+1/K), V1, step keys ----------------
// blk 0..1023: copy/transpose; blk 1024..1535: V1 column dots; blk 1536..1539: keys
__global__ __launch_bounds__(256) void setup_fused(
    const float* __restrict__ P, const float* __restrict__ initp,
    float* __restrict__ POW0, float* __restrict__ PTp,
    float* __restrict__ INITROW, float* __restrict__ V1,
    int* __restrict__ runCount, int* __restrict__ maxLdev,
    uint32_t* __restrict__ KEY0, uint32_t* __restrict__ KEY1,
    uint32_t ks0, uint32_t ks1) {
  int blk = blockIdx.x;
  if (blk < 1024) {
    int id = blk * 256 + threadIdx.x;
    int r = id >> 9, c = id & 511;
    float v = P[id];
    POW0[id] = v;
    PTp[c * 512 + r] = v + 0.001953125f;   // + 1/K, bit-identical to inline add
    if (id < 512) INITROW[id] = initp[id];
    if (id == 0) { *runCount = 0; *maxLdev = 1; }
  } else if (blk < 1536) {
    // V1[c] = sum_j initp[j] * P[j][c], f64 tree-reduce, block per column
    int c = blk - 1024;
    int t = threadIdx.x;
    double acc = (double)initp[t] * (double)P[t * 512 + c]
               + (double)initp[t + 256] * (double)P[(t + 256) * 512 + c];
#pragma unroll
    for (int o = 32; o >= 1; o >>= 1) acc += __shfl_down(acc, o);
    __shared__ double sred[4];
    if ((t & 63) == 0) sred[t >> 6] = acc;
    __syncthreads();
    if (t == 0) V1[c] = (float)((sred[0] + sred[1]) + (sred[2] + sred[3]));
  } else {
    int j = (blk - 1536) * 256 + threadIdx.x;
    if (j < T_ - 1) {
      uint32_t a, b;
      step_key(ks0, ks1, j, a, b);
      KEY0[j] = a; KEY1[j] = b;
    }
  }
}

// Parallel per-b scan: message offsets, run extraction, maxL.
__global__ __launch_bounds__(1024) void setup_offsets_par(
    const int* __restrict__ data, const float* __restrict__ masks,
    int* __restrict__ off, int lmax, int initoff,
    int* __restrict__ runs, int* __restrict__ runCount, int* __restrict__ maxLdev) {
  __shared__ int prevObs[1024];
  __shared__ int nextObs[1024];
  int b = blockIdx.x;
  int t = threadIdx.x;
  bool obs = masks[b * T_ + t] > 0.0f;
  prevObs[t] = obs ? t : -1;
  nextObs[t] = obs ? t : T_;
  __syncthreads();
  for (int o = 1; o < 1024; o <<= 1) {
    int pv = (t >= o) ? prevObs[t - o] : -1;
    int nv = (t + o < 1024) ? nextObs[t + o] : T_;
    __syncthreads();
    if (pv > prevObs[t]) prevObs[t] = pv;
    if (nv < nextObs[t]) nextObs[t] = nv;
    __syncthreads();
  }
  int t0 = (t > 0) ? prevObs[t - 1] : -1;
  int idx = b * T_ + t;
  if (obs) off[idx] = -1;
  else if (t0 >= 0) {
    int L = t - t0; if (L > lmax) L = lmax;
    off[idx] = (L - 1) * POWSLOT + data[b * T_ + t0] * 512;
  } else if (t == 0) off[idx] = initoff;
  else {
    int L = t; if (L > lmax) L = lmax;
    off[idx] = (L - 1) * POWSLOT + 512 * 512;   // init-chain V row
  }
  if (!obs && t <= T_ - 2 && (t == 0 || masks[b * T_ + t - 1] > 0.0f)) {
    int te = nextObs[t] - 1; if (te > T_ - 2) te = T_ - 2;
    int r = atomicAdd(runCount, 1);
    if (r < MAXRUNS) {
      runs[r] = (b << 20) | (t << 10) | te;
      int maxL = (t == 0) ? te : (te - t + 1);
      if (maxL > 1) atomicMax(maxLdev, maxL);
    }
  }
}

// ---------------- Power GEMM via f64 MFMA (self-calibrating D layout) ----------------
// 32x32 block tile, 4 waves (2x2 of 16x16), Kc=32 chunks.
__global__ __launch_bounds__(256) void power_gemm_mfma(float* __restrict__ POW, int m,
                                                       int lmax, const int* __restrict__ maxLdev) {
  int y = blockIdx.y;
  {
    int gate = *maxLdev; if (gate > lmax) gate = lmax;
    if (y + 1 + m > gate) return;
  }
  const float* A  = POW + (size_t)y * POWSLOT;
  const float* Bm = POW + (size_t)(m - 1) * POWSLOT;
  float* C        = POW + (size_t)(y + m) * POWSLOT;
  __shared__ double As[32][33];   // [k][r]
  __shared__ double Bs[32][33];   // [k][c]
  int tid = threadIdx.x;
  int lane = tid & 63;
  int wv = tid >> 6;              // wave 0..3
  int wr = wv >> 1, wc = wv & 1;  // 2x2 wave grid
  int q = lane >> 4, r16 = lane & 15;
  int r0 = (blockIdx.x >> 4) * 32;   // 17 row tiles cover 513 rows
  int c0 = (blockIdx.x & 15) * 32;   // 16 col tiles

  // --- calibrate D mapping: (lane,reg) -> (i,j). Exact integer probes. ---
  f64x4 z = {0.0, 0.0, 0.0, 0.0};
  f64x4 d1 = __builtin_amdgcn_mfma_f64_16x16x4f64((double)r16, 1.0, z, 0, 0, 0);   // D=4i
  f64x4 d2 = __builtin_amdgcn_mfma_f64_16x16x4f64(1.0, (double)r16, z, 0, 0, 0);   // D=4j
  int ir[4], ic[4];
#pragma unroll
  for (int v = 0; v < 4; ++v) {
    ir[v] = (((int)d1[v]) >> 2) & 15;
    ic[v] = (((int)d2[v]) >> 2) & 15;
  }

  // staging: thread loads 4 consecutive f32 of an A row and a B row.
  int sr = tid >> 3;                 // 0..31
  int sk4 = (tid & 7) * 4;           // 0,4,..,28
  int ar = r0 + sr; if (ar > 512) ar = 512;   // clamp (stores guarded)

  f64x4 acc = {0.0, 0.0, 0.0, 0.0};
  for (int kc = 0; kc < 512; kc += 32) {
    float4 av = *(const float4*)(A + (size_t)ar * 512 + kc + sk4);
    float4 bv = *(const float4*)(Bm + (size_t)(kc + sr) * 512 + c0 + sk4);
    __syncthreads();                 // previous chunk's reads done
    As[sk4 + 0][sr] = (double)av.x;
    As[sk4 + 1][sr] = (double)av.y;
    As[sk4 + 2][sr] = (double)av.z;
    As[sk4 + 3][sr] = (double)av.w;
    Bs[sr][sk4 + 0] = (double)bv.x;
    Bs[sr][sk4 + 1] = (double)bv.y;
    Bs[sr][sk4 + 2] = (double)bv.z;
    Bs[sr][sk4 + 3] = (double)bv.w;
    __syncthreads();
#pragma unroll
    for (int ks = 0; ks < 8; ++ks) {
      double a = As[ks * 4 + q][wr * 16 + r16];   // A[m=r16][k=ks*4+q]
      double b = Bs[ks * 4 + q][wc * 16 + r16];   // B[k][n=r16]
      acc = __builtin_amdgcn_mfma_f64_16x16x4f64(a, b, acc, 0, 0, 0);
    }
  }
#pragma unroll
  for (int v = 0; v < 4; ++v) {
    int gr = r0 + wr * 16 + ir[v];
    int gc = c0 + wc * 16 + ic[v];
    if (gr < 513) C[(size_t)gr * 512 + gc] = (float)acc[v];
  }
}

// ---------------- Backward sampling: wave-per-(run,chain), STATIC strided ----------------
// Lane l owns k = 8l..8l+7 (float4x2 msg/ptp loads). Argmax via fmaxf
// butterfly + ballot (lowest lane with max = smallest k; within-lane scan
// keeps smallest j). Per-k values bit-identical to R11/R12.
// Unit u -> run u>>2, chain u&3. wid = blockIdx*4+wv, stride NW=32768:
// block x's first pass covers exactly run x's 4 chains (shared msg row).
__global__ __launch_bounds__(256) void backward_run(
    const int* __restrict__ data, const float* __restrict__ masks,
    const float* __restrict__ wsF, const int* __restrict__ off,
    const float* __restrict__ PTp,
    const uint32_t* __restrict__ KEY0, const uint32_t* __restrict__ KEY1,
    const int* __restrict__ runs, const int* __restrict__ runCount,
    int* __restrict__ out) {
  // folded fill_out: deterministic outputs (observed t, and t = T-1)
  {
    int id = blockIdx.x * 256 + threadIdx.x;
    if (id < NCHAIN * T_) {
      int t = id & (T_ - 1);
      int b = id >> 12;               // id>>10 = chain, chain>>2 = b
      if (t == T_ - 1 || masks[b * T_ + t] > 0.0f) out[id] = data[b * T_ + t];
    }
  }
  int lane = threadIdx.x & 63;
  int wv = threadIdx.x >> 6;
  int wid = blockIdx.x * 4 + wv;
  const int NW = BWD_BLOCKS * 4;
  int total = *runCount;
  if (total > MAXRUNS) total = MAXRUNS;
  total <<= 2;                        // units = runs x 4 chains
  const float* wsL = wsF + (lane << 3);
  const float* ptL = PTp + (lane << 3);
  for (int u = wid; u < total; u += NW) {
    int run = runs[u >> 2];
    int ci = u & 3;
    int b = run >> 20, ta = (run >> 10) & 1023, tb = run & 1023;
    int s = data[b * T_ + tb + 1];    // mask=1 or t=T-1: deterministic anchor
    uint32_t ebase = ((uint32_t)b << 11) | ((uint32_t)ci << 9) | ((uint32_t)(lane << 3));
    const int* offb = off + b * T_;
    int* outp = out + (((b << 2) | ci) * T_);
    for (int t = tb; t >= ta; --t) {
      int j = (T_ - 2) - t;
      uint32_t kj0 = KEY0[j], kj1 = KEY1[j];
      int o = offb[t];
      float4 m0 = *(const float4*)(wsL + o);
      float4 m1 = *(const float4*)(wsL + o + 4);
      const float* prow = ptL + ((size_t)s << 9);
      float4 p0 = *(const float4*)(prow);
      float4 p1 = *(const float4*)(prow + 4);
      float x0 = fmaf(m0.x, p0.x, 1e-20f) * gumbel_scale(rng_bits(kj0, kj1, ebase + 0u));
      float x1 = fmaf(m0.y, p0.y, 1e-20f) * gumbel_scale(rng_bits(kj0, kj1, ebase + 1u));
      float x2 = fmaf(m0.z, p0.z, 1e-20f) * gumbel_scale(rng_bits(kj0, kj1, ebase + 2u));
      float x3 = fmaf(m0.w, p0.w, 1e-20f) * gumbel_scale(rng_bits(kj0, kj1, ebase + 3u));
      float x4 = fmaf(m1.x, p1.x, 1e-20f) * gumbel_scale(rng_bits(kj0, kj1, ebase + 4u));
      float x5 = fmaf(m1.y, p1.y, 1e-20f) * gumbel_scale(rng_bits(kj0, kj1, ebase + 5u));
      float x6 = fmaf(m1.z, p1.z, 1e-20f) * gumbel_scale(rng_bits(kj0, kj1, ebase + 6u));
      float x7 = fmaf(m1.w, p1.w, 1e-20f) * gumbel_scale(rng_bits(kj0, kj1, ebase + 7u));
      // local argmax, strict > keeps smallest j on ties
      float bv = x0; int bj = 0;
      if (x1 > bv) { bv = x1; bj = 1; }
      if (x2 > bv) { bv = x2; bj = 2; }
      if (x3 > bv) { bv = x3; bj = 3; }
      if (x4 > bv) { bv = x4; bj = 4; }
      if (x5 > bv) { bv = x5; bj = 5; }
      if (x6 > bv) { bv = x6; bj = 6; }
      if (x7 > bv) { bv = x7; bj = 7; }
      // wave max (butterfly -> all lanes hold identical max)
      float wm = bv;
#pragma unroll
      for (int d = 1; d < 64; d <<= 1) wm = fmaxf(wm, __shfl_xor(wm, d));
      unsigned long long bal = __ballot(bv == wm);
      int wl = __ffsll(bal) - 1;       // lowest lane with the max = smallest k
      int jw = __shfl(bj, wl);
      s = (wl << 3) + jw;              // uniform across wave
      if (lane == 0) outp[t] = s;
    }
  }
}

// ---------------- Launcher ----------------
extern "C" void kernel_launch(void* const* d_in, const int* in_sizes, int n_in,
                              void* d_out, int out_size, void* d_ws, size_t ws_size,
                              hipStream_t stream) {
  const int* data = (const int*)d_in[0];
  const float* masks = (const float*)d_in[1];
  const float* initp = (const float*)d_in[2];
  const float* P = (const float*)d_in[3];
  int* out = (int*)d_out;

  int lmax = LMAX_WANT;
  {
    long long fixed = 512LL * 512 + 512 + (long long)B_ * T_ + 2 * (T_ - 1) + MAXRUNS + 64;
    long long avail = (long long)(ws_size / 4) - fixed;
    long long fit = avail / POWSLOT;
    if (fit < lmax) lmax = (fit < 1) ? 1 : (int)fit;
  }
  float* wsF = (float*)d_ws;
  float* POW = wsF;
  float* PTp = wsF + (size_t)lmax * POWSLOT;
  float* INITROW = PTp + 512 * 512;
  int* off = (int*)(INITROW + 512);
  uint32_t* KEY0 = (uint32_t*)(off + B_ * T_);
  uint32_t* KEY1 = KEY0 + (T_ - 1);
  int* runs = (int*)(KEY1 + (T_ - 1));
  int* runCount = runs + MAXRUNS;
  int* maxLdev = runCount + 1;
  int initoff = lmax * POWSLOT + 512 * 512;   // INITROW position in floats

  uint32_t ks0, ks1;
#if JAX_PARTITIONABLE
  tf2x32(0u, 42u, 0u, 1u, ks0, ks1);
#else
  {
    uint32_t a0, b0, a1, b1;
    tf2x32(0u, 42u, 0u, 2u, a0, b0);
    tf2x32(0u, 42u, 1u, 3u, a1, b1);
    ks0 = b0; ks1 = b1;
  }
#endif

  hipLaunchKernelGGL(setup_fused, dim3(1540), dim3(256), 0, stream,
                     P, initp, POW, PTp, INITROW, POW + 512 * 512,
                     runCount, maxLdev, KEY0, KEY1, ks0, ks1);
  hipLaunchKernelGGL(setup_offsets_par, dim3(B_), dim3(1024), 0, stream,
                     data, masks, off, lmax, initoff, runs, runCount, maxLdev);
  int m = 1;
  while (m < lmax) {
    int count = lmax - m; if (count > m) count = m;
    hipLaunchKernelGGL(power_gemm_mfma, dim3(17 * 16, count), dim3(256), 0, stream,
                       POW, m, lmax, maxLdev);
    m += count;
  }
  hipLaunchKernelGGL(backward_run, dim3(BWD_BLOCKS), dim3(256), 0, stream,
                     data, masks, wsF, off, PTp, KEY0, KEY1, runs, runCount, out);
}